// Round 2
// baseline (380.340 us; speedup 1.0000x reference)
//
#include <hip/hip_runtime.h>
#include <hip/hip_bf16.h>

#define BB  16384
#define F   40
#define D   64
#define E   64
#define LDQ 72   // QB stride (el): 144 B = 9*16 B -> 16B-aligned rows, conflict-free b128
#define LDV 56   // VT stride (el): 112 B = 7*16 B -> 16B-aligned rows, conflict-free b128

typedef __bf16 bf16;
typedef __bf16 bf16x8 __attribute__((ext_vector_type(8)));
typedef __bf16 bf16x4 __attribute__((ext_vector_type(4)));
typedef float  f32x4  __attribute__((ext_vector_type(4)));

// MFMA 16x16x32 bf16 layouts:
//   A-frag: lane holds A[m = lane&15][k = (lane>>4)*8 + j]
//   B-frag: lane holds B[k = (lane>>4)*8 + j][n = lane&15]
//   C/D   : lane holds C[row = (lane>>4)*4 + r][col = lane&15]
// Note: B-frag of M == A-frag of M^T (same lane data). So X fragments loaded
// as A-operands double as the B-operand (X^T) of the S matmul.

// ---- prep: G = Wq*Wk^T (fp32), then pack G/Wv/Wr into B-fragment order (bf16) ----
// frag element [( (nt*2+kt)*64 + lane )*8 + j] = W[kt*32 + (lane>>4)*8 + j][nt*16 + (lane&15)]
__global__ __launch_bounds__(256)
void prep_weights(const float* __restrict__ Wq, const float* __restrict__ Wk,
                  const float* __restrict__ Wv, const float* __restrict__ Wr,
                  bf16* __restrict__ ws)
{
    __shared__ float Gs[64 * 64];
    const int tid = threadIdx.x;
    for (int i = tid; i < 64 * 64; i += 256) {
        int dd = i >> 6, ee = i & 63;          // G[d][d'] = sum_e Wq[d][e]*Wk[d'][e]
        float s = 0.f;
        for (int e = 0; e < 64; ++e) s += Wq[dd * 64 + e] * Wk[ee * 64 + e];
        Gs[i] = s;
    }
    __syncthreads();
    for (int f = tid; f < 4096; f += 256) {
        int j = f & 7, lane = (f >> 3) & 63, kt = (f >> 9) & 1, nt = f >> 10;
        int dd = kt * 32 + (lane >> 4) * 8 + j;
        int ee = nt * 16 + (lane & 15);
        ws[f]        = (bf16)Gs[dd * 64 + ee];
        ws[4096 + f] = (bf16)Wv[dd * 64 + ee];
        ws[8192 + f] = (bf16)Wr[dd * 64 + ee];
    }
}

// ---- main: one wave per block, one batch per wave, wave-private LDS, no barriers ----
__global__ __launch_bounds__(64, 3)
void attn_fused(const float* __restrict__ X,
                const bf16* __restrict__ wfrag,
                float* __restrict__ Out)
{
    __shared__ bf16 QB[48 * LDQ];        // XG (q' = X@G), later P
    __shared__ bf16 VT[64 * LDV + 16];   // v^T: VT[e][k'], k' in [0,48) written; [48,56)+tail zeroed

    const int lane = threadIdx.x;        // 0..63
    const int l16  = lane & 15;
    const int quad = lane >> 4;
    const int b    = blockIdx.x;
    const float* Xb = X + (size_t)b * (F * D);

    // zero VT k' in [48,56) for every e-row, plus the 16-el tail (row-63 kt=1 read
    // overruns into it). These are never written by v-stores; uninit LDS could be NaN
    // and NaN*0 = NaN in the PV MFMA.
    {
        bf16x8 z = {};
        *(bf16x8*)&VT[lane * LDV + 48] = z;
        if (lane < 2) *(bf16x8*)&VT[64 * LDV + lane * 8] = z;
    }

    // ---- X A-fragments straight from global (fp32 -> bf16), row-clamped ----
    bf16x8 xf[3][2];
    #pragma unroll
    for (int mt = 0; mt < 3; ++mt) {
        int row = mt * 16 + l16; if (row >= F) row = F - 1;  // finite pad rows, no OOB
        #pragma unroll
        for (int kt = 0; kt < 2; ++kt) {
            const float* p = Xb + row * D + kt * 32 + quad * 8;
            float4 u0 = *(const float4*)p;
            float4 u1 = *(const float4*)(p + 4);
            bf16x8 f;
            f[0] = (bf16)u0.x; f[1] = (bf16)u0.y; f[2] = (bf16)u0.z; f[3] = (bf16)u0.w;
            f[4] = (bf16)u1.x; f[5] = (bf16)u1.y; f[6] = (bf16)u1.z; f[7] = (bf16)u1.w;
            xf[mt][kt] = f;
        }
    }

    const bf16x8* gF = (const bf16x8*)wfrag;           // G  fragments (8)
    const bf16x8* vF = (const bf16x8*)(wfrag + 4096);  // Wv fragments (8)
    const bf16x8* rF = (const bf16x8*)(wfrag + 8192);  // Wr fragments (8)

    // ---- residual: racc = X @ Wr (stays in registers as PV C-input) ----
    f32x4 racc[3][4];
    #pragma unroll
    for (int nt = 0; nt < 4; ++nt) {
        bf16x8 b0 = gF ? rF[(nt * 2 + 0) * 64 + lane] : bf16x8{};
        bf16x8 b1 = rF[(nt * 2 + 1) * 64 + lane];
        #pragma unroll
        for (int mt = 0; mt < 3; ++mt) {
            f32x4 acc = {0.f, 0.f, 0.f, 0.f};
            acc = __builtin_amdgcn_mfma_f32_16x16x32_bf16(xf[mt][0], b0, acc, 0, 0, 0);
            acc = __builtin_amdgcn_mfma_f32_16x16x32_bf16(xf[mt][1], b1, acc, 0, 0, 0);
            racc[mt][nt] = acc;
        }
    }

    // ---- v = X @ Wv, stored transposed: VT[e][k'] (4 C-elements contiguous) ----
    #pragma unroll
    for (int nt = 0; nt < 4; ++nt) {
        bf16x8 b0 = vF[(nt * 2 + 0) * 64 + lane];
        bf16x8 b1 = vF[(nt * 2 + 1) * 64 + lane];
        #pragma unroll
        for (int mt = 0; mt < 3; ++mt) {
            f32x4 acc = {0.f, 0.f, 0.f, 0.f};
            acc = __builtin_amdgcn_mfma_f32_16x16x32_bf16(xf[mt][0], b0, acc, 0, 0, 0);
            acc = __builtin_amdgcn_mfma_f32_16x16x32_bf16(xf[mt][1], b1, acc, 0, 0, 0);
            int col = nt * 16 + l16;       // e
            int r0  = mt * 16 + quad * 4;  // k'
            bf16x4 pk;
            pk[0] = (bf16)acc[0]; pk[1] = (bf16)acc[1];
            pk[2] = (bf16)acc[2]; pk[3] = (bf16)acc[3];
            *(bf16x4*)&VT[col * LDV + r0] = pk;
        }
    }

    // ---- q' = X @ G, stored row-major in QB (rows 40..47 garbage-but-finite) ----
    #pragma unroll
    for (int nt = 0; nt < 4; ++nt) {
        bf16x8 b0 = gF[(nt * 2 + 0) * 64 + lane];
        bf16x8 b1 = gF[(nt * 2 + 1) * 64 + lane];
        #pragma unroll
        for (int mt = 0; mt < 3; ++mt) {
            f32x4 acc = {0.f, 0.f, 0.f, 0.f};
            acc = __builtin_amdgcn_mfma_f32_16x16x32_bf16(xf[mt][0], b0, acc, 0, 0, 0);
            acc = __builtin_amdgcn_mfma_f32_16x16x32_bf16(xf[mt][1], b1, acc, 0, 0, 0);
            int col = nt * 16 + l16;
            int r0  = mt * 16 + quad * 4;
            #pragma unroll
            for (int r = 0; r < 4; ++r) QB[(r0 + r) * LDQ + col] = (bf16)acc[r];
        }
    }

    // ---- S = q' @ X^T  (B-operand is xf: B-frag of X^T == A-frag of X) ----
    bf16x8 qf[3][2];
    #pragma unroll
    for (int mt = 0; mt < 3; ++mt)
        #pragma unroll
        for (int kt = 0; kt < 2; ++kt)
            qf[mt][kt] = *(const bf16x8*)&QB[(mt * 16 + l16) * LDQ + kt * 32 + quad * 8];
    f32x4 sacc[3][3];
    #pragma unroll
    for (int smt = 0; smt < 3; ++smt)
        #pragma unroll
        for (int snt = 0; snt < 3; ++snt) {
            f32x4 acc = {0.f, 0.f, 0.f, 0.f};
            acc = __builtin_amdgcn_mfma_f32_16x16x32_bf16(qf[smt][0], xf[snt][0], acc, 0, 0, 0);
            acc = __builtin_amdgcn_mfma_f32_16x16x32_bf16(qf[smt][1], xf[snt][1], acc, 0, 0, 0);
            sacc[smt][snt] = acc;
        }

    // ---- softmax over cols; write P (bf16) into QB, cols 48..63 zeroed ----
    const bool mask2 = (l16 >= 8);   // snt==2 covers cols 32..47; cols >= 40 invalid
    #pragma unroll
    for (int smt = 0; smt < 3; ++smt) {
        #pragma unroll
        for (int r = 0; r < 4; ++r) {
            float s0 = sacc[smt][0][r];
            float s1 = sacc[smt][1][r];
            float s2 = mask2 ? -1e30f : sacc[smt][2][r];
            float m = fmaxf(fmaxf(s0, s1), s2);
            #pragma unroll
            for (int off = 1; off < 16; off <<= 1)
                m = fmaxf(m, __shfl_xor(m, off, 64));
            float e0 = __expf(s0 - m);
            float e1 = __expf(s1 - m);
            float e2 = mask2 ? 0.f : __expf(s2 - m);
            float sum = e0 + e1 + e2;
            #pragma unroll
            for (int off = 1; off < 16; off <<= 1)
                sum += __shfl_xor(sum, off, 64);
            float inv = 1.0f / sum;
            int row = smt * 16 + quad * 4 + r;
            if (row < F) {
                QB[row * LDQ + l16]      = (bf16)(e0 * inv);
                QB[row * LDQ + 16 + l16] = (bf16)(e1 * inv);
                QB[row * LDQ + 32 + l16] = (bf16)(e2 * inv);
                QB[row * LDQ + 48 + l16] = (bf16)0.f;   // neutralize K-pad of PV
            }
        }
    }

    // ---- O = P @ v + racc, relu, store ----
    bf16x8 pf[3][2];
    #pragma unroll
    for (int mt = 0; mt < 3; ++mt)
        #pragma unroll
        for (int kt = 0; kt < 2; ++kt)
            pf[mt][kt] = *(const bf16x8*)&QB[(mt * 16 + l16) * LDQ + kt * 32 + quad * 8];
    #pragma unroll
    for (int nt = 0; nt < 4; ++nt) {
        bf16x8 v0 = *(const bf16x8*)&VT[(nt * 16 + l16) * LDV + 0  + quad * 8];
        bf16x8 v1 = *(const bf16x8*)&VT[(nt * 16 + l16) * LDV + 32 + quad * 8];
        #pragma unroll
        for (int mt = 0; mt < 3; ++mt) {
            f32x4 acc = racc[mt][nt];
            acc = __builtin_amdgcn_mfma_f32_16x16x32_bf16(pf[mt][0], v0, acc, 0, 0, 0);
            acc = __builtin_amdgcn_mfma_f32_16x16x32_bf16(pf[mt][1], v1, acc, 0, 0, 0);
            int col = nt * 16 + l16;
            #pragma unroll
            for (int r = 0; r < 4; ++r) {
                int row = mt * 16 + quad * 4 + r;
                if (row < F)
                    Out[(size_t)b * (F * E) + row * E + col] = fmaxf(acc[r], 0.f);
            }
        }
    }
}

extern "C" void kernel_launch(void* const* d_in, const int* in_sizes, int n_in,
                              void* d_out, int out_size, void* d_ws, size_t ws_size,
                              hipStream_t stream) {
    const float* X  = (const float*)d_in[0];
    const float* Wq = (const float*)d_in[1];
    const float* Wk = (const float*)d_in[2];
    const float* Wv = (const float*)d_in[3];
    const float* Wr = (const float*)d_in[4];
    float* Out = (float*)d_out;
    bf16* ws = (bf16*)d_ws;   // 12288 bf16 = 24 KB of fragment-packed weights

    prep_weights<<<1, 256, 0, stream>>>(Wq, Wk, Wv, Wr, ws);
    attn_fused<<<BB, 64, 0, stream>>>(X, ws, Out);
}